// Round 3
// baseline (173.054 us; speedup 1.0000x reference)
//
#include <hip/hip_runtime.h>

#define DEG 32

typedef _Float16 half8 __attribute__((ext_vector_type(8)));
typedef float f32x4 __attribute__((ext_vector_type(4)));

#define EXP2F(x)  __builtin_amdgcn_exp2f(x)
#define SIN_REV(x) __builtin_amdgcn_sinf(x)   // sin(2*pi*x), x in revolutions
#define COS_REV(x) __builtin_amdgcn_cosf(x)   // cos(2*pi*x)
#define RCPF(x)   __builtin_amdgcn_rcpf(x)
#define INV_2PI   0.15915494309189535f
#define TWO_LOG2E 2.8853900817779268f

// tanh-form GELU; max abs deviation from exact erf-GELU ~3e-4 (threshold 1.76e-2)
__device__ __forceinline__ float gelu_f(float x){
  float z = 0.7978845608028654f * (x + 0.044715f * x * x * x);
  float e = EXP2F(TWO_LOG2E * z);            // e = exp(2z)
  float th = 1.0f - 2.0f * RCPF(1.0f + e);   // tanh(z)
  return 0.5f * x * (1.0f + th);
}

// Fill sA[64][200] (fp16, +8 pad halves/row -> 400B stride, 2-way LDS aliasing = free)
// with node embeddings: feat@W_in + b_in + sincos(pos).
__device__ __forceinline__ void embed_fill(_Float16 (*sA)[200],
    const float (*sPos)[3], const float (*sFeat)[3],
    const float* sWin, const float* sBin, int t){
  const float NEG_L2_10K_O32 = -0.41524101186092046f; // -log2(10000)/32
  #pragma unroll
  for (int r = 0; r < 24; r++){
    int id = t + 256 * r;          // 0..6143 over 64 rows x 96 channel-pairs
    int e  = id / 96;
    int cp = id - e * 96;
    int c0 = cp * 2;
    int axis = c0 >> 6;
    int u0   = c0 & 63;            // even; both channels same axis & same sin/cos half
    float p  = sPos[e][axis];
    float f0 = sFeat[e][0], f1 = sFeat[e][1], f2 = sFeat[e][2];
    float v0 = f0*sWin[c0]   + f1*sWin[192+c0]   + f2*sWin[384+c0]   + sBin[c0];
    float v1 = f0*sWin[c0+1] + f1*sWin[192+c0+1] + f2*sWin[384+c0+1] + sBin[c0+1];
    bool isCos = (u0 >= 32);
    int  i0 = isCos ? (u0 - 32) : u0;
    float om0 = EXP2F((float)i0       * NEG_L2_10K_O32);
    float om1 = EXP2F((float)(i0 + 1) * NEG_L2_10K_O32);
    float a0 = p * om0 * INV_2PI, a1 = p * om1 * INV_2PI;  // revolutions, in [0, 0.16)
    v0 += isCos ? COS_REV(a0) : SIN_REV(a0);
    v1 += isCos ? COS_REV(a1) : SIN_REV(a1);
    _Float16 h0 = (_Float16)v0, h1 = (_Float16)v1;
    unsigned int packed = (unsigned int)__builtin_bit_cast(unsigned short, h0)
                        | ((unsigned int)__builtin_bit_cast(unsigned short, h1) << 16);
    *reinterpret_cast<unsigned int*>(&sA[e][c0]) = packed;
  }
}

// Per-wave B fragments: 48-col slice of Bt[n][k] (fp16, pre-transposed), 18x 16B loads.
__device__ __forceinline__ void load_bfrags(half8 Bf[3][6], const _Float16* Bt,
    int ldk, int koff, int wave, int ln15, int grp){
  #pragma unroll
  for (int n = 0; n < 3; n++){
    const _Float16* rowp = Bt + (wave*48 + n*16 + ln15) * ldk + koff + grp*8;
    #pragma unroll
    for (int k6 = 0; k6 < 6; k6++)
      Bf[n][k6] = *reinterpret_cast<const half8*>(rowp + k6*32);
  }
}

__device__ __forceinline__ void mfma_loop(f32x4 acc[4][3], const _Float16 (*sA)[200],
    const half8 Bf[3][6], int ln15, int grp){
  #pragma unroll
  for (int k6 = 0; k6 < 6; k6++){
    half8 Af[4];
    #pragma unroll
    for (int m = 0; m < 4; m++)
      Af[m] = *reinterpret_cast<const half8*>(&sA[m*16 + ln15][k6*32 + grp*8]);
    #pragma unroll
    for (int m = 0; m < 4; m++)
      #pragma unroll
      for (int n = 0; n < 3; n++)
        acc[m][n] = __builtin_amdgcn_mfma_f32_16x16x32_f16(Af[m], Bf[n][k6], acc[m][n], 0, 0, 0);
  }
}

// K0: W1[384][192] -> w1t fp16 [192 n][384 k]; W2 -> w2t fp16 [192][192] scaled by 1/32.
__global__ void k0_prep(const float* __restrict__ W1, const float* __restrict__ W2,
    _Float16* __restrict__ w1t, _Float16* __restrict__ w2t){
  int id = blockIdx.x * 256 + threadIdx.x;
  if (id < 73728){
    int k = id / 192, n = id - k * 192;
    w1t[n*384 + k] = (_Float16)W1[id];
  } else if (id < 73728 + 36864){
    int i2 = id - 73728;
    int k = i2 / 192, n = i2 - k * 192;
    w2t[n*192 + k] = (_Float16)(W2[i2] * 0.03125f);
  }
}

// K1: a_dst[8192][192] = x_dst @ W1_bot + b1   (128 blocks x 64 supernodes)
__global__ __launch_bounds__(256) void k1_dst(const int* __restrict__ dst_idx,
    const float* __restrict__ feat, const float* __restrict__ pos,
    const float* __restrict__ W_in, const float* __restrict__ b_in,
    const float* __restrict__ b1, const _Float16* __restrict__ w1t,
    float* __restrict__ a_dst){
  __shared__ float sWin[576], sBin[192];
  __shared__ float sPos[64][3], sFeat[64][3];
  __shared__ _Float16 sA[64][200];
  int blk = blockIdx.x, t = threadIdx.x;
  for (int i = t; i < 576; i += 256) sWin[i] = W_in[i];
  for (int i = t; i < 192; i += 256) sBin[i] = b_in[i];
  if (t < 64){
    int node = dst_idx[(blk*64 + t) * DEG];
    sFeat[t][0] = feat[3*node]; sFeat[t][1] = feat[3*node+1]; sFeat[t][2] = feat[3*node+2];
    sPos[t][0]  = pos[3*node];  sPos[t][1]  = pos[3*node+1];  sPos[t][2]  = pos[3*node+2];
  }
  __syncthreads();
  embed_fill(sA, sPos, sFeat, sWin, sBin, t);
  int wave = t >> 6, lane = t & 63, ln15 = lane & 15, grp = lane >> 4;
  half8 Bf[3][6];
  load_bfrags(Bf, w1t, 384, 192, wave, ln15, grp);   // bottom half of W1
  f32x4 acc[4][3];
  #pragma unroll
  for (int m = 0; m < 4; m++)
    #pragma unroll
    for (int n = 0; n < 3; n++) acc[m][n] = (f32x4){0.f, 0.f, 0.f, 0.f};
  __syncthreads();
  mfma_loop(acc, sA, Bf, ln15, grp);
  #pragma unroll
  for (int n = 0; n < 3; n++){
    int col = wave*48 + n*16 + ln15;
    float bias = b1[col];
    #pragma unroll
    for (int m = 0; m < 4; m++)
      #pragma unroll
      for (int r = 0; r < 4; r++){
        int row = blk*64 + m*16 + grp*4 + r;
        a_dst[row*192 + col] = acc[m][n][r] + bias;
      }
  }
}

// K2: per 64-edge tile (2 supernodes): embed src, GEMM vs W1_top, +a_dst, GELU,
// row-sum per supernode -> S1 fp16 [8192][192].
__global__ __launch_bounds__(256) void k2_edge(const int* __restrict__ src_idx,
    const float* __restrict__ feat, const float* __restrict__ pos,
    const float* __restrict__ W_in, const float* __restrict__ b_in,
    const _Float16* __restrict__ w1t, const float* __restrict__ a_dst,
    _Float16* __restrict__ S1){
  __shared__ float sWin[576], sBin[192];
  __shared__ float sPos[64][3], sFeat[64][3];
  __shared__ float sAdst[2][192];
  __shared__ _Float16 sA[64][200];
  int blk = blockIdx.x, t = threadIdx.x;
  int e0 = blk * 64;
  for (int i = t; i < 576; i += 256) sWin[i] = W_in[i];
  for (int i = t; i < 192; i += 256) sBin[i] = b_in[i];
  for (int i = t; i < 384; i += 256) ((float*)sAdst)[i] = a_dst[blk*384 + i];
  if (t < 64){
    int node = src_idx[e0 + t];
    sFeat[t][0] = feat[3*node]; sFeat[t][1] = feat[3*node+1]; sFeat[t][2] = feat[3*node+2];
    sPos[t][0]  = pos[3*node];  sPos[t][1]  = pos[3*node+1];  sPos[t][2]  = pos[3*node+2];
  }
  __syncthreads();
  embed_fill(sA, sPos, sFeat, sWin, sBin, t);
  int wave = t >> 6, lane = t & 63, ln15 = lane & 15, grp = lane >> 4;
  half8 Bf[3][6];
  load_bfrags(Bf, w1t, 384, 0, wave, ln15, grp);     // top half of W1
  f32x4 acc[4][3];
  #pragma unroll
  for (int m = 0; m < 4; m++)
    #pragma unroll
    for (int n = 0; n < 3; n++) acc[m][n] = (f32x4){0.f, 0.f, 0.f, 0.f};
  __syncthreads();
  mfma_loop(acc, sA, Bf, ln15, grp);
  // epilogue: +a_dst, gelu, sum rows 0..31 (supernode h=0) and 32..63 (h=1)
  #pragma unroll
  for (int h = 0; h < 2; h++){
    #pragma unroll
    for (int n = 0; n < 3; n++){
      int col = wave*48 + n*16 + ln15;
      float ad = sAdst[h][col];
      float cs = 0.f;
      #pragma unroll
      for (int mm = 0; mm < 2; mm++){
        f32x4 a = acc[h*2 + mm][n];
        #pragma unroll
        for (int r = 0; r < 4; r++) cs += gelu_f(a[r] + ad);
      }
      cs += __shfl_xor(cs, 16, 64);
      cs += __shfl_xor(cs, 32, 64);
      if (grp == 0)
        S1[(blk*2 + h)*192 + col] = (_Float16)cs;
    }
  }
}

// K3: out[8192][192] = S1 @ (W2/32) + b2  (128 blocks x 64 rows; no LDS)
__global__ __launch_bounds__(256) void k3_out(const _Float16* __restrict__ S1,
    const _Float16* __restrict__ w2t, const float* __restrict__ b2,
    float* __restrict__ out){
  int blk = blockIdx.x, t = threadIdx.x;
  int wave = t >> 6, lane = t & 63, ln15 = lane & 15, grp = lane >> 4;
  half8 Bf[3][6];
  load_bfrags(Bf, w2t, 192, 0, wave, ln15, grp);
  f32x4 acc[4][3];
  #pragma unroll
  for (int m = 0; m < 4; m++)
    #pragma unroll
    for (int n = 0; n < 3; n++) acc[m][n] = (f32x4){0.f, 0.f, 0.f, 0.f};
  #pragma unroll
  for (int k6 = 0; k6 < 6; k6++){
    half8 Af[4];
    #pragma unroll
    for (int m = 0; m < 4; m++)
      Af[m] = *reinterpret_cast<const half8*>(S1 + (blk*64 + m*16 + ln15)*192 + k6*32 + grp*8);
    #pragma unroll
    for (int m = 0; m < 4; m++)
      #pragma unroll
      for (int n = 0; n < 3; n++)
        acc[m][n] = __builtin_amdgcn_mfma_f32_16x16x32_f16(Af[m], Bf[n][k6], acc[m][n], 0, 0, 0);
  }
  #pragma unroll
  for (int n = 0; n < 3; n++){
    int col = wave*48 + n*16 + ln15;
    float bias = b2[col];
    #pragma unroll
    for (int m = 0; m < 4; m++)
      #pragma unroll
      for (int r = 0; r < 4; r++)
        out[(blk*64 + m*16 + grp*4 + r)*192 + col] = acc[m][n][r] + bias;
  }
}

extern "C" void kernel_launch(void* const* d_in, const int* in_sizes, int n_in,
                              void* d_out, int out_size, void* d_ws, size_t ws_size,
                              hipStream_t stream) {
  const float* feat   = (const float*)d_in[0];
  const float* pos    = (const float*)d_in[1];
  const int*   src_i  = (const int*)  d_in[2];
  const int*   dst_i  = (const int*)  d_in[3];
  const float* W_in   = (const float*)d_in[4];
  const float* b_in   = (const float*)d_in[5];
  const float* W1     = (const float*)d_in[6];
  const float* b1     = (const float*)d_in[7];
  const float* W2     = (const float*)d_in[8];
  const float* b2     = (const float*)d_in[9];
  float* out = (float*)d_out;

  char* ws = (char*)d_ws;
  _Float16* w1t   = (_Float16*)(ws);                // 192*384*2 = 147456 B
  _Float16* w2t   = (_Float16*)(ws + 147456);       // 192*192*2 =  73728 B
  float*    a_dst = (float*)   (ws + 221184);       // 8192*192*4 = 6291456 B
  _Float16* S1    = (_Float16*)(ws + 6512640);      // 8192*192*2 = 3145728 B
  // total ws use: 9658368 B

  k0_prep<<<432, 256, 0, stream>>>(W1, W2, w1t, w2t);
  k1_dst <<<128, 256, 0, stream>>>(dst_i, feat, pos, W_in, b_in, b1, w1t, a_dst);
  k2_edge<<<4096, 256, 0, stream>>>(src_i, feat, pos, W_in, b_in, w1t, a_dst, S1);
  k3_out <<<128, 256, 0, stream>>>(S1, w2t, b2, out);
}

// Round 5
// 152.748 us; speedup vs baseline: 1.1329x; 1.1329x over previous
//
#include <hip/hip_runtime.h>

#define DEG 32
#define SAW 232   // sA row stride in halves (464 B = 29*16B: 16B-aligned, 2-way-bank-free)

typedef _Float16 half8 __attribute__((ext_vector_type(8)));
typedef __fp16 fp16x2 __attribute__((ext_vector_type(2)));
typedef float f32x4 __attribute__((ext_vector_type(4)));
typedef int int4v __attribute__((ext_vector_type(4)));

#define EXP2F(x)   __builtin_amdgcn_exp2f(x)
#define SIN_REV(x) __builtin_amdgcn_sinf(x)   // sin(2*pi*x)
#define COS_REV(x) __builtin_amdgcn_cosf(x)   // cos(2*pi*x)
#define RCPF(x)    __builtin_amdgcn_rcpf(x)
#define INV_2PI    0.15915494309189535f
#define TWO_LOG2E  2.8853900817779268f
#define NEG_L2_10K_O32 -0.41524101186092046f  // -log2(10000)/32

// tanh-form GELU; deviation from erf-GELU ~3e-4 (threshold 1.76e-2)
__device__ __forceinline__ float gelu_f(float x){
  float z = 0.7978845608028654f * (x + 0.044715f * x * x * x);
  float e = EXP2F(TWO_LOG2E * z);
  float th = 1.0f - 2.0f * RCPF(1.0f + e);
  return 0.5f * x * (1.0f + th);
}

__device__ __forceinline__ int pkh(float a, float b){
  fp16x2 p = __builtin_amdgcn_cvt_pkrtz(a, b);   // v_cvt_pkrtz_f16_f32
  return __builtin_bit_cast(int, p);
}

// Build A-tile sA[64][SAW]: cols 0..191 = sincos(pos), 192..194 = feat (fp16), 195..223 = 0.
// Trig fill: 192 threads = 3 waves (w=axis) x (g=freq-block, r16); stores hit the
// 2-way-free bank pattern (20*r16+4g). Wave 3 stages feat cols directly from global.
__device__ __forceinline__ void build_tile(_Float16 (*sA)[SAW], float (*sPos)[3],
    float* sOmg, const int* __restrict__ idx, int idx_stride, int base,
    const float* __restrict__ feat, const float* __restrict__ pos, int t){
  if (t < 32) sOmg[t] = EXP2F((float)t * NEG_L2_10K_O32) * INV_2PI;
  if (t < 64){
    int node = idx[(base + t) * idx_stride];
    sPos[t][0] = pos[3*node]; sPos[t][1] = pos[3*node+1]; sPos[t][2] = pos[3*node+2];
  }
  if (t >= 192){
    int e = t - 192;
    int node = idx[(base + e) * idx_stride];
    float f0 = feat[3*node], f1 = feat[3*node+1], f2 = feat[3*node+2];
    int4v v0; v0[0] = pkh(f0, f1); v0[1] = pkh(f2, 0.f); v0[2] = 0; v0[3] = 0;
    int4v z; z[0] = 0; z[1] = 0; z[2] = 0; z[3] = 0;
    *reinterpret_cast<int4v*>(&sA[e][192]) = v0;
    *reinterpret_cast<int4v*>(&sA[e][200]) = z;
    *reinterpret_cast<int4v*>(&sA[e][208]) = z;
    *reinterpret_cast<int4v*>(&sA[e][216]) = z;
  }
  __syncthreads();
  if (t < 192){
    int lane = t & 63, w = t >> 6;          // w = axis
    int r16 = lane & 15, g = lane >> 4;     // freq block: freqs 8g..8g+7
    float om[8];
    #pragma unroll
    for (int j = 0; j < 8; j++) om[j] = sOmg[8*g + j];
    #pragma unroll
    for (int rr = 0; rr < 4; rr++){
      int row = r16 + rr*16;
      float p = sPos[row][w];
      float a[8];
      #pragma unroll
      for (int j = 0; j < 8; j++) a[j] = p * om[j];
      int4v sv, cv;
      #pragma unroll
      for (int j = 0; j < 4; j++){
        sv[j] = pkh(SIN_REV(a[2*j]), SIN_REV(a[2*j+1]));
        cv[j] = pkh(COS_REV(a[2*j]), COS_REV(a[2*j+1]));
      }
      int ch = w*8 + g;                     // sin chunk; cos at ch+4
      *reinterpret_cast<int4v*>(&sA[row][8*ch])     = sv;
      *reinterpret_cast<int4v*>(&sA[row][8*(ch+4)]) = cv;
    }
  }
  __syncthreads();
}

// 64x192 = A(64x224) @ B(224x192), B fp16 [192 n][224 k] from global (L1/L2-resident).
__device__ __forceinline__ void gemm_tile(f32x4 acc[4][3], const _Float16 (*sA)[SAW],
    const _Float16* __restrict__ Bt, int ln15, int grp, int wave){
  #pragma unroll
  for (int k6 = 0; k6 < 7; k6++){
    half8 Af[4];
    #pragma unroll
    for (int m = 0; m < 4; m++)
      Af[m] = *reinterpret_cast<const half8*>(&sA[m*16 + ln15][k6*32 + grp*8]);
    #pragma unroll
    for (int n = 0; n < 3; n++){
      half8 Bf = *reinterpret_cast<const half8*>(Bt + (wave*48 + n*16 + ln15)*224 + k6*32 + grp*8);
      #pragma unroll
      for (int m = 0; m < 4; m++)
        acc[m][n] = __builtin_amdgcn_mfma_f32_16x16x32_f16(Af[m], Bf, acc[m][n], 0, 0, 0);
    }
  }
}

// K0: precompute folded weights.
//  w1tc[n][k] (fp16,[192][224]): k<192 -> W1_top[k][n]; k=192..194 -> (W_in@W1_top)[k-192][n]; else 0
//  w1bc: same with W1_bot.  w2t[n][k] = W2[k][n]/32.
//  bias_c[n] = b1[n] + (b_in@W1_top)[n] + (b_in@W1_bot)[n]
__global__ void k0_prep(const float* __restrict__ W_in, const float* __restrict__ b_in,
    const float* __restrict__ W1, const float* __restrict__ b1,
    const float* __restrict__ W2,
    _Float16* __restrict__ w1tc, _Float16* __restrict__ w1bc,
    _Float16* __restrict__ w2t, float* __restrict__ bias_c){
  int id = blockIdx.x * 256 + threadIdx.x;
  if (id < 86016){
    int half_sel = id / 43008;          // 0: top, 1: bottom
    int i = id - half_sel * 43008;
    int n = i / 224, k = i - n * 224;
    const float* Wh = W1 + half_sel * 192 * 192;
    _Float16* dst = half_sel ? w1bc : w1tc;
    if (k < 192) dst[i] = (_Float16)Wh[k*192 + n];
    else if (k < 195){
      int r = k - 192;
      float s = 0.f;
      for (int m = 0; m < 192; m++) s += W_in[r*192 + m] * Wh[m*192 + n];
      dst[i] = (_Float16)s;
    } else dst[i] = (_Float16)0.f;
  } else if (id < 122880){
    int i = id - 86016;
    int n = i / 192, k = i - n * 192;
    w2t[i] = (_Float16)(W2[k*192 + n] * 0.03125f);
  } else if (id < 123072){
    int n = id - 122880;
    float s = b1[n];
    for (int m = 0; m < 192; m++) s += b_in[m] * (W1[m*192 + n] + W1[(192+m)*192 + n]);
    bias_c[n] = s;
  }
}

// K1: a_dst[8192][192] (fp16) = embed(dst) @ w1bc + bias_c
__global__ __launch_bounds__(256) void k1_dst(const int* __restrict__ dst_idx,
    const float* __restrict__ feat, const float* __restrict__ pos,
    const _Float16* __restrict__ w1bc, const float* __restrict__ bias_c,
    _Float16* __restrict__ a_dst){
  __shared__ _Float16 sA[64][SAW];
  __shared__ float sPos[64][3];
  __shared__ float sOmg[32];
  int blk = blockIdx.x, t = threadIdx.x;
  build_tile(sA, sPos, sOmg, dst_idx, DEG, blk*64, feat, pos, t);
  int wave = t >> 6, lane = t & 63, ln15 = lane & 15, grp = lane >> 4;
  f32x4 acc[4][3];
  #pragma unroll
  for (int m = 0; m < 4; m++)
    #pragma unroll
    for (int n = 0; n < 3; n++) acc[m][n] = (f32x4){0.f, 0.f, 0.f, 0.f};
  gemm_tile(acc, sA, w1bc, ln15, grp, wave);
  #pragma unroll
  for (int n = 0; n < 3; n++){
    int col = wave*48 + n*16 + ln15;
    float bias = bias_c[col];
    #pragma unroll
    for (int m = 0; m < 4; m++)
      #pragma unroll
      for (int r = 0; r < 4; r++)
        a_dst[(blk*64 + m*16 + grp*4 + r)*192 + col] = (_Float16)(acc[m][n][r] + bias);
  }
}

// K2: per 64-edge tile (2 supernodes): embed src, @w1tc, +a_dst, GELU, row-sum -> S1 fp16.
__global__ __launch_bounds__(256) void k2_edge(const int* __restrict__ src_idx,
    const float* __restrict__ feat, const float* __restrict__ pos,
    const _Float16* __restrict__ w1tc, const _Float16* __restrict__ a_dst,
    _Float16* __restrict__ S1){
  __shared__ _Float16 sA[64][SAW];
  __shared__ float sPos[64][3];
  __shared__ float sOmg[32];
  int blk = blockIdx.x, t = threadIdx.x;
  build_tile(sA, sPos, sOmg, src_idx, 1, blk*64, feat, pos, t);
  int wave = t >> 6, lane = t & 63, ln15 = lane & 15, grp = lane >> 4;
  f32x4 acc[4][3];
  #pragma unroll
  for (int m = 0; m < 4; m++)
    #pragma unroll
    for (int n = 0; n < 3; n++) acc[m][n] = (f32x4){0.f, 0.f, 0.f, 0.f};
  gemm_tile(acc, sA, w1tc, ln15, grp, wave);
  const _Float16* adp = a_dst + blk*2*192;
  #pragma unroll
  for (int h = 0; h < 2; h++){
    #pragma unroll
    for (int n = 0; n < 3; n++){
      int col = wave*48 + n*16 + ln15;
      float ad = (float)adp[h*192 + col];
      float cs = 0.f;
      #pragma unroll
      for (int mm = 0; mm < 2; mm++){
        f32x4 a = acc[h*2 + mm][n];
        #pragma unroll
        for (int r = 0; r < 4; r++) cs += gelu_f(a[r] + ad);
      }
      cs += __shfl_xor(cs, 16, 64);
      cs += __shfl_xor(cs, 32, 64);
      if (grp == 0)
        S1[(blk*2 + h)*192 + col] = (_Float16)cs;
    }
  }
}

// K3: out[8192][192] = S1 @ (W2/32) + b2
__global__ __launch_bounds__(256) void k3_out(const _Float16* __restrict__ S1,
    const _Float16* __restrict__ w2t, const float* __restrict__ b2,
    float* __restrict__ out){
  int blk = blockIdx.x, t = threadIdx.x;
  int wave = t >> 6, lane = t & 63, ln15 = lane & 15, grp = lane >> 4;
  f32x4 acc[4][3];
  #pragma unroll
  for (int m = 0; m < 4; m++)
    #pragma unroll
    for (int n = 0; n < 3; n++) acc[m][n] = (f32x4){0.f, 0.f, 0.f, 0.f};
  #pragma unroll
  for (int k6 = 0; k6 < 6; k6++){
    half8 Af[4];
    #pragma unroll
    for (int m = 0; m < 4; m++)
      Af[m] = *reinterpret_cast<const half8*>(S1 + (blk*64 + m*16 + ln15)*192 + k6*32 + grp*8);
    #pragma unroll
    for (int n = 0; n < 3; n++){
      half8 Bf = *reinterpret_cast<const half8*>(w2t + (wave*48 + n*16 + ln15)*192 + k6*32 + grp*8);
      #pragma unroll
      for (int m = 0; m < 4; m++)
        acc[m][n] = __builtin_amdgcn_mfma_f32_16x16x32_f16(Af[m], Bf, acc[m][n], 0, 0, 0);
    }
  }
  #pragma unroll
  for (int n = 0; n < 3; n++){
    int col = wave*48 + n*16 + ln15;
    float bias = b2[col];
    #pragma unroll
    for (int m = 0; m < 4; m++)
      #pragma unroll
      for (int r = 0; r < 4; r++)
        out[(blk*64 + m*16 + grp*4 + r)*192 + col] = acc[m][n][r] + bias;
  }
}

extern "C" void kernel_launch(void* const* d_in, const int* in_sizes, int n_in,
                              void* d_out, int out_size, void* d_ws, size_t ws_size,
                              hipStream_t stream) {
  const float* feat   = (const float*)d_in[0];
  const float* pos    = (const float*)d_in[1];
  const int*   src_i  = (const int*)  d_in[2];
  const int*   dst_i  = (const int*)  d_in[3];
  const float* W_in   = (const float*)d_in[4];
  const float* b_in   = (const float*)d_in[5];
  const float* W1     = (const float*)d_in[6];
  const float* b1     = (const float*)d_in[7];
  const float* W2     = (const float*)d_in[8];
  const float* b2     = (const float*)d_in[9];
  float* out = (float*)d_out;

  char* ws = (char*)d_ws;
  _Float16* w1tc   = (_Float16*)(ws);                 // 192*224*2 =  86016 B
  _Float16* w1bc   = (_Float16*)(ws + 86016);         //              86016 B
  _Float16* w2t    = (_Float16*)(ws + 172032);        // 192*192*2 =  73728 B
  float*    bias_c = (float*)   (ws + 245760);        //                768 B
  _Float16* a_dst  = (_Float16*)(ws + 246528);        // 8192*192*2 = 3145728 B
  _Float16* S1     = (_Float16*)(ws + 3392256);       // 8192*192*2 = 3145728 B
  // total ws use: 6537984 B

  k0_prep<<<481, 256, 0, stream>>>(W_in, b_in, W1, b1, W2, w1tc, w1bc, w2t, bias_c);
  k1_dst <<<128, 256, 0, stream>>>(dst_i, feat, pos, w1bc, bias_c, a_dst);
  k2_edge<<<4096, 256, 0, stream>>>(src_i, feat, pos, w1tc, a_dst, S1);
  k3_out <<<128, 256, 0, stream>>>(S1, w2t, b2, out);
}

// Round 6
// 152.275 us; speedup vs baseline: 1.1365x; 1.0031x over previous
//
#include <hip/hip_runtime.h>

#define DEG 32
#define SAW 232   // sA row stride in halves (464 B = 29*16B: 16B-aligned, 2-way-bank-free)

typedef _Float16 half8 __attribute__((ext_vector_type(8)));
typedef __fp16 fp16x2 __attribute__((ext_vector_type(2)));
typedef float f32x4 __attribute__((ext_vector_type(4)));
typedef int int4v __attribute__((ext_vector_type(4)));

#define EXP2F(x)   __builtin_amdgcn_exp2f(x)
#define SIN_REV(x) __builtin_amdgcn_sinf(x)   // sin(2*pi*x)
#define COS_REV(x) __builtin_amdgcn_cosf(x)   // cos(2*pi*x)
#define RCPF(x)    __builtin_amdgcn_rcpf(x)
#define INV_2PI    0.15915494309189535f
#define NEG_L2_10K_O32 -0.41524101186092046f  // -log2(10000)/32

// 7-inst tanh-GELU: 0.5x(1+tanh(z)) = x - x/(1+e^{2z}), 2z*log2e = x*(c1 + c2*x^2)
__device__ __forceinline__ float gelu_f(float x){
  float x2 = x * x;
  float t  = __builtin_fmaf(0.10294824f, x2, 2.3022079f);
  float e  = EXP2F(x * t);
  float r  = RCPF(1.0f + e);
  return __builtin_fmaf(-x, r, x);
}

__device__ __forceinline__ int pkh(float a, float b){
  fp16x2 p = __builtin_amdgcn_cvt_pkrtz(a, b);   // v_cvt_pkrtz_f16_f32
  return __builtin_bit_cast(int, p);
}

__device__ __forceinline__ float wave_reduce(float v){
  #pragma unroll
  for (int s = 1; s < 64; s <<= 1) v += __shfl_xor(v, s, 64);
  return v;
}

// ---- shared tile-build pieces -------------------------------------------
// phase A: gathers (t<64 pos; t>=192 feat->LDS cols 192..223) + omega table
__device__ __forceinline__ void tile_gather(_Float16 (*sA)[SAW], float (*sPos)[3],
    float* sOmg, const int* __restrict__ idx, int idx_stride, int base,
    const float* __restrict__ feat, const float* __restrict__ pos, int t){
  if (t < 32) sOmg[t] = EXP2F((float)t * NEG_L2_10K_O32) * INV_2PI;
  if (t < 64){
    int node = idx[(base + t) * idx_stride];
    sPos[t][0] = pos[3*node]; sPos[t][1] = pos[3*node+1]; sPos[t][2] = pos[3*node+2];
  }
  if (t >= 192){
    int e = t - 192;
    int node = idx[(base + e) * idx_stride];
    float f0 = feat[3*node], f1 = feat[3*node+1], f2 = feat[3*node+2];
    int4v v0; v0[0] = pkh(f0, f1); v0[1] = pkh(f2, 0.f); v0[2] = 0; v0[3] = 0;
    int4v z; z[0] = 0; z[1] = 0; z[2] = 0; z[3] = 0;
    *reinterpret_cast<int4v*>(&sA[e][192]) = v0;
    *reinterpret_cast<int4v*>(&sA[e][200]) = z;
    *reinterpret_cast<int4v*>(&sA[e][208]) = z;
    *reinterpret_cast<int4v*>(&sA[e][216]) = z;
  }
}

// phase B: trig fill, t<192: 3 waves (w=axis) x (g=freq-block, r16)
__device__ __forceinline__ void tile_trig(_Float16 (*sA)[SAW], const float (*sPos)[3],
    const float* sOmg, int t){
  if (t < 192){
    int lane = t & 63, w = t >> 6;
    int r16 = lane & 15, g = lane >> 4;
    float om[8];
    #pragma unroll
    for (int j = 0; j < 8; j++) om[j] = sOmg[8*g + j];
    #pragma unroll
    for (int rr = 0; rr < 4; rr++){
      int row = r16 + rr*16;
      float p = sPos[row][w];
      float a[8];
      #pragma unroll
      for (int j = 0; j < 8; j++) a[j] = p * om[j];
      int4v sv, cv;
      #pragma unroll
      for (int j = 0; j < 4; j++){
        sv[j] = pkh(SIN_REV(a[2*j]), SIN_REV(a[2*j+1]));
        cv[j] = pkh(COS_REV(a[2*j]), COS_REV(a[2*j+1]));
      }
      int ch = w*8 + g;                     // sin chunk; cos at ch+4
      *reinterpret_cast<int4v*>(&sA[row][8*ch])     = sv;
      *reinterpret_cast<int4v*>(&sA[row][8*(ch+4)]) = cv;
    }
  }
}

// 64x192 = A(64x224) @ B(224x192), B streamed from global (k1 path)
__device__ __forceinline__ void gemm_tile(f32x4 acc[4][3], const _Float16 (*sA)[SAW],
    const _Float16* __restrict__ Bt, int ln15, int grp, int wave){
  #pragma unroll
  for (int k6 = 0; k6 < 7; k6++){
    half8 Af[4];
    #pragma unroll
    for (int m = 0; m < 4; m++)
      Af[m] = *reinterpret_cast<const half8*>(&sA[m*16 + ln15][k6*32 + grp*8]);
    #pragma unroll
    for (int n = 0; n < 3; n++){
      half8 Bf = *reinterpret_cast<const half8*>(Bt + (wave*48 + n*16 + ln15)*224 + k6*32 + grp*8);
      #pragma unroll
      for (int m = 0; m < 4; m++)
        acc[m][n] = __builtin_amdgcn_mfma_f32_16x16x32_f16(Af[m], Bf, acc[m][n], 0, 0, 0);
    }
  }
}

// ---- K0: folded-weight prep (fully wave-parallel, no serial dot loops) ----
//  w1tc[n][k]: k<192 -> W1_top[k][n]; k=192+r -> (W_in@W1_top)[r][n]; k>=195 -> 0
//  w1bc: same for W1_bot.  w2t[n][k] = W2[k][n]/32.
//  bias_c[n] = b1[n] + (b_in@W1_top)[n] + (b_in@W1_bot)[n]
__global__ void k0_prep(const float* __restrict__ W_in, const float* __restrict__ b_in,
    const float* __restrict__ W1, const float* __restrict__ b1,
    const float* __restrict__ W2,
    _Float16* __restrict__ w1tc, _Float16* __restrict__ w1bc,
    _Float16* __restrict__ w2t, float* __restrict__ bias_c){
  int id = blockIdx.x * 256 + threadIdx.x;
  if (id < 86016){                       // transpose + zero-pad (skip fold cols)
    int half_sel = id / 43008;
    int i = id - half_sel * 43008;
    int n = i / 224, k = i - n * 224;
    const float* Wh = W1 + half_sel * 192 * 192;
    _Float16* dst = half_sel ? w1bc : w1tc;
    if (k < 192)      dst[i] = (_Float16)Wh[k*192 + n];
    else if (k >= 195) dst[i] = (_Float16)0.f;
  } else if (id < 122880){               // w2t
    int i = id - 86016;
    int n = i / 192, k = i - n * 192;
    w2t[i] = (_Float16)(W2[k*192 + n] * 0.03125f);
  } else if (id < 135168){               // bias_c: one wave per n
    int o = (id - 122880) >> 6, lane = id & 63;
    float s = 0.f;
    #pragma unroll
    for (int u = 0; u < 3; u++){
      int m = lane + 64*u;
      s += b_in[m] * (W1[m*192 + o] + W1[(m+192)*192 + o]);
    }
    s = wave_reduce(s);
    if (lane == 0) bias_c[o] = s + b1[o];
  } else if (id < 208896){               // fold cols: one wave per (half,r,n)
    int o = (id - 135168) >> 6, lane = id & 63;
    int half_sel = o / 576;
    int rem = o - half_sel * 576;
    int r = rem / 192, n = rem - r * 192;
    const float* Wh = W1 + half_sel * 192 * 192;
    float s = 0.f;
    #pragma unroll
    for (int u = 0; u < 3; u++){
      int m = lane + 64*u;
      s += W_in[r*192 + m] * Wh[m*192 + n];
    }
    s = wave_reduce(s);
    if (lane == 0){
      _Float16* dst = half_sel ? w1bc : w1tc;
      dst[n*224 + 192 + r] = (_Float16)s;
    }
  }
}

// ---- K1: a_dst[8192][192] (fp16) = embed(dst) @ w1bc + bias_c ----
__global__ __launch_bounds__(256) void k1_dst(const int* __restrict__ dst_idx,
    const float* __restrict__ feat, const float* __restrict__ pos,
    const _Float16* __restrict__ w1bc, const float* __restrict__ bias_c,
    _Float16* __restrict__ a_dst){
  __shared__ _Float16 sA[64][SAW];
  __shared__ float sPos[64][3];
  __shared__ float sOmg[32];
  int blk = blockIdx.x, t = threadIdx.x;
  tile_gather(sA, sPos, sOmg, dst_idx, DEG, blk*64, feat, pos, t);
  __syncthreads();
  tile_trig(sA, sPos, sOmg, t);
  __syncthreads();
  int wave = t >> 6, lane = t & 63, ln15 = lane & 15, grp = lane >> 4;
  f32x4 acc[4][3];
  #pragma unroll
  for (int m = 0; m < 4; m++)
    #pragma unroll
    for (int n = 0; n < 3; n++) acc[m][n] = (f32x4){0.f, 0.f, 0.f, 0.f};
  gemm_tile(acc, sA, w1bc, ln15, grp, wave);
  #pragma unroll
  for (int n = 0; n < 3; n++){
    int col = wave*48 + n*16 + ln15;
    float bias = bias_c[col];
    #pragma unroll
    for (int m = 0; m < 4; m++)
      #pragma unroll
      for (int r = 0; r < 4; r++)
        a_dst[(blk*64 + m*16 + grp*4 + r)*192 + col] = (_Float16)(acc[m][n][r] + bias);
  }
}

// ---- K2: embed src tile, @w1tc (B preloaded in regs), +a_dst, GELU, row-sum ----
__global__ __launch_bounds__(256) void k2_edge(const int* __restrict__ src_idx,
    const float* __restrict__ feat, const float* __restrict__ pos,
    const _Float16* __restrict__ w1tc, const _Float16* __restrict__ a_dst,
    _Float16* __restrict__ S1){
  __shared__ _Float16 sA[64][SAW];
  __shared__ float sPos[64][3];
  __shared__ float sOmg[32];
  int blk = blockIdx.x, t = threadIdx.x;
  int wave = t >> 6, lane = t & 63, ln15 = lane & 15, grp = lane >> 4;

  // issue gathers first (longest latency), then B preload (hides under trig)
  tile_gather(sA, sPos, sOmg, src_idx, 1, blk*64, feat, pos, t);
  half8 Breg[21];
  {
    const _Float16* bp = w1tc + (wave*48 + ln15)*224 + grp*8;
    #pragma unroll
    for (int n = 0; n < 3; n++)
      #pragma unroll
      for (int k6 = 0; k6 < 7; k6++)
        Breg[n*7 + k6] = *reinterpret_cast<const half8*>(bp + n*16*224 + k6*32);
  }
  __syncthreads();
  tile_trig(sA, sPos, sOmg, t);
  __syncthreads();

  f32x4 acc[4][3];
  #pragma unroll
  for (int m = 0; m < 4; m++)
    #pragma unroll
    for (int n = 0; n < 3; n++) acc[m][n] = (f32x4){0.f, 0.f, 0.f, 0.f};
  #pragma unroll
  for (int k6 = 0; k6 < 7; k6++){
    half8 Af[4];
    #pragma unroll
    for (int m = 0; m < 4; m++)
      Af[m] = *reinterpret_cast<const half8*>(&sA[m*16 + ln15][k6*32 + grp*8]);
    #pragma unroll
    for (int n = 0; n < 3; n++)
      #pragma unroll
      for (int m = 0; m < 4; m++)
        acc[m][n] = __builtin_amdgcn_mfma_f32_16x16x32_f16(Af[m], Breg[n*7 + k6], acc[m][n], 0, 0, 0);
  }

  const _Float16* adp = a_dst + blk*2*192;
  #pragma unroll
  for (int h = 0; h < 2; h++){
    #pragma unroll
    for (int n = 0; n < 3; n++){
      int col = wave*48 + n*16 + ln15;
      float ad = (float)adp[h*192 + col];
      float cs = 0.f;
      #pragma unroll
      for (int mm = 0; mm < 2; mm++){
        f32x4 a = acc[h*2 + mm][n];
        #pragma unroll
        for (int r = 0; r < 4; r++) cs += gelu_f(a[r] + ad);
      }
      cs += __shfl_xor(cs, 16, 64);
      cs += __shfl_xor(cs, 32, 64);
      if (grp == 0)
        S1[(blk*2 + h)*192 + col] = (_Float16)cs;
    }
  }
}

// ---- K3: out[8192][192] = S1 @ (W2/32) + b2 ----
__global__ __launch_bounds__(256) void k3_out(const _Float16* __restrict__ S1,
    const _Float16* __restrict__ w2t, const float* __restrict__ b2,
    float* __restrict__ out){
  int blk = blockIdx.x, t = threadIdx.x;
  int wave = t >> 6, lane = t & 63, ln15 = lane & 15, grp = lane >> 4;
  f32x4 acc[4][3];
  #pragma unroll
  for (int m = 0; m < 4; m++)
    #pragma unroll
    for (int n = 0; n < 3; n++) acc[m][n] = (f32x4){0.f, 0.f, 0.f, 0.f};
  #pragma unroll
  for (int k6 = 0; k6 < 6; k6++){
    half8 Af[4];
    #pragma unroll
    for (int m = 0; m < 4; m++)
      Af[m] = *reinterpret_cast<const half8*>(S1 + (blk*64 + m*16 + ln15)*192 + k6*32 + grp*8);
    #pragma unroll
    for (int n = 0; n < 3; n++){
      half8 Bf = *reinterpret_cast<const half8*>(w2t + (wave*48 + n*16 + ln15)*192 + k6*32 + grp*8);
      #pragma unroll
      for (int m = 0; m < 4; m++)
        acc[m][n] = __builtin_amdgcn_mfma_f32_16x16x32_f16(Af[m], Bf, acc[m][n], 0, 0, 0);
    }
  }
  #pragma unroll
  for (int n = 0; n < 3; n++){
    int col = wave*48 + n*16 + ln15;
    float bias = b2[col];
    #pragma unroll
    for (int m = 0; m < 4; m++)
      #pragma unroll
      for (int r = 0; r < 4; r++)
        out[(blk*64 + m*16 + grp*4 + r)*192 + col] = acc[m][n][r] + bias;
  }
}

extern "C" void kernel_launch(void* const* d_in, const int* in_sizes, int n_in,
                              void* d_out, int out_size, void* d_ws, size_t ws_size,
                              hipStream_t stream) {
  const float* feat   = (const float*)d_in[0];
  const float* pos    = (const float*)d_in[1];
  const int*   src_i  = (const int*)  d_in[2];
  const int*   dst_i  = (const int*)  d_in[3];
  const float* W_in   = (const float*)d_in[4];
  const float* b_in   = (const float*)d_in[5];
  const float* W1     = (const float*)d_in[6];
  const float* b1     = (const float*)d_in[7];
  const float* W2     = (const float*)d_in[8];
  const float* b2     = (const float*)d_in[9];
  float* out = (float*)d_out;

  char* ws = (char*)d_ws;
  _Float16* w1tc   = (_Float16*)(ws);                 // 192*224*2 =  86016 B
  _Float16* w1bc   = (_Float16*)(ws + 86016);         //              86016 B
  _Float16* w2t    = (_Float16*)(ws + 172032);        // 192*192*2 =  73728 B
  float*    bias_c = (float*)   (ws + 245760);        //                768 B
  _Float16* a_dst  = (_Float16*)(ws + 246528);        // 8192*192*2 = 3145728 B
  _Float16* S1     = (_Float16*)(ws + 3392256);       // 8192*192*2 = 3145728 B
  // total ws use: 6537984 B

  k0_prep<<<816, 256, 0, stream>>>(W_in, b_in, W1, b1, W2, w1tc, w1bc, w2t, bias_c);
  k1_dst <<<128, 256, 0, stream>>>(dst_i, feat, pos, w1bc, bias_c, a_dst);
  k2_edge<<<4096, 256, 0, stream>>>(src_i, feat, pos, w1tc, a_dst, S1);
  k3_out <<<128, 256, 0, stream>>>(S1, w2t, b2, out);
}

// Round 8
// 138.305 us; speedup vs baseline: 1.2513x; 1.1010x over previous
//
#include <hip/hip_runtime.h>

#define DEG 32
#define SAW 232   // sA row stride in halves (464 B: 16B-aligned, 2-way-bank-free)
#define TILES 8   // 64-edge tiles per block; grid = 262144/(64*TILES) = 512

typedef _Float16 half8 __attribute__((ext_vector_type(8)));
typedef __fp16 fp16x2 __attribute__((ext_vector_type(2)));
typedef float f32x4 __attribute__((ext_vector_type(4)));
typedef int int4v __attribute__((ext_vector_type(4)));

#define EXP2F(x)   __builtin_amdgcn_exp2f(x)
#define SIN_REV(x) __builtin_amdgcn_sinf(x)   // sin(2*pi*x)
#define COS_REV(x) __builtin_amdgcn_cosf(x)   // cos(2*pi*x)
#define RCPF(x)    __builtin_amdgcn_rcpf(x)
#define INV_2PI    0.15915494309189535f
#define NEG_L2_10K_O32 -0.41524101186092046f  // -log2(10000)/32

// 7-inst tanh-GELU: x - x/(1+e^{2z}), with 2z*log2e = x*(c1 + c2*x^2)
__device__ __forceinline__ float gelu_f(float x){
  float x2 = x * x;
  float t  = __builtin_fmaf(0.10294824f, x2, 2.3022079f);
  float e  = EXP2F(x * t);
  float r  = RCPF(1.0f + e);
  return __builtin_fmaf(-x, r, x);
}

__device__ __forceinline__ int pkh(float a, float b){
  fp16x2 p = __builtin_amdgcn_cvt_pkrtz(a, b);
  return __builtin_bit_cast(int, p);
}

__device__ __forceinline__ float wave_reduce(float v){
  #pragma unroll
  for (int s = 1; s < 64; s <<= 1) v += __shfl_xor(v, s, 64);
  return v;
}

// trig fill: t<192, 3 waves (w=axis) x (g=freq-block, r16) -> sA cols 0..191
__device__ __forceinline__ void tile_trig(_Float16 (*sA)[SAW], const float (*sPos)[3],
    const float* sOmg, int t){
  if (t < 192){
    int lane = t & 63, w = t >> 6;
    int r16 = lane & 15, g = lane >> 4;
    float om[8];
    #pragma unroll
    for (int j = 0; j < 8; j++) om[j] = sOmg[8*g + j];
    #pragma unroll
    for (int rr = 0; rr < 4; rr++){
      int row = r16 + rr*16;
      float p = sPos[row][w];
      float a[8];
      #pragma unroll
      for (int j = 0; j < 8; j++) a[j] = p * om[j];
      int4v sv, cv;
      #pragma unroll
      for (int j = 0; j < 4; j++){
        sv[j] = pkh(SIN_REV(a[2*j]), SIN_REV(a[2*j+1]));
        cv[j] = pkh(COS_REV(a[2*j]), COS_REV(a[2*j+1]));
      }
      int ch = w*8 + g;                     // sin chunk; cos at ch+4
      *reinterpret_cast<int4v*>(&sA[row][8*ch])     = sv;
      *reinterpret_cast<int4v*>(&sA[row][8*(ch+4)]) = cv;
    }
  }
}

// 64x192 = A(64x224) @ B(224x192), B streamed from global (k1 path)
__device__ __forceinline__ void gemm_tile(f32x4 acc[4][3], const _Float16 (*sA)[SAW],
    const _Float16* __restrict__ Bt, int ln15, int grp, int wave){
  #pragma unroll
  for (int k6 = 0; k6 < 7; k6++){
    half8 Af[4];
    #pragma unroll
    for (int m = 0; m < 4; m++)
      Af[m] = *reinterpret_cast<const half8*>(&sA[m*16 + ln15][k6*32 + grp*8]);
    #pragma unroll
    for (int n = 0; n < 3; n++){
      half8 Bf = *reinterpret_cast<const half8*>(Bt + (wave*48 + n*16 + ln15)*224 + k6*32 + grp*8);
      #pragma unroll
      for (int m = 0; m < 4; m++)
        acc[m][n] = __builtin_amdgcn_mfma_f32_16x16x32_f16(Af[m], Bf, acc[m][n], 0, 0, 0);
    }
  }
}

// ---- K0: folded-weight prep (wave-parallel) ----
__global__ void k0_prep(const float* __restrict__ W_in, const float* __restrict__ b_in,
    const float* __restrict__ W1, const float* __restrict__ b1,
    const float* __restrict__ W2,
    _Float16* __restrict__ w1tc, _Float16* __restrict__ w1bc,
    _Float16* __restrict__ w2t, float* __restrict__ bias_c){
  int id = blockIdx.x * 256 + threadIdx.x;
  if (id < 86016){
    int half_sel = id / 43008;
    int i = id - half_sel * 43008;
    int n = i / 224, k = i - n * 224;
    const float* Wh = W1 + half_sel * 192 * 192;
    _Float16* dst = half_sel ? w1bc : w1tc;
    if (k < 192)      dst[i] = (_Float16)Wh[k*192 + n];
    else if (k >= 195) dst[i] = (_Float16)0.f;
  } else if (id < 122880){
    int i = id - 86016;
    int n = i / 192, k = i - n * 192;
    w2t[i] = (_Float16)(W2[k*192 + n] * 0.03125f);
  } else if (id < 135168){
    int o = (id - 122880) >> 6, lane = id & 63;
    float s = 0.f;
    #pragma unroll
    for (int u = 0; u < 3; u++){
      int m = lane + 64*u;
      s += b_in[m] * (W1[m*192 + o] + W1[(m+192)*192 + o]);
    }
    s = wave_reduce(s);
    if (lane == 0) bias_c[o] = s + b1[o];
  } else if (id < 208896){
    int o = (id - 135168) >> 6, lane = id & 63;
    int half_sel = o / 576;
    int rem = o - half_sel * 576;
    int r = rem / 192, n = rem - r * 192;
    const float* Wh = W1 + half_sel * 192 * 192;
    float s = 0.f;
    #pragma unroll
    for (int u = 0; u < 3; u++){
      int m = lane + 64*u;
      s += W_in[r*192 + m] * Wh[m*192 + n];
    }
    s = wave_reduce(s);
    if (lane == 0){
      _Float16* dst = half_sel ? w1bc : w1tc;
      dst[n*224 + 192 + r] = (_Float16)s;
    }
  }
}

// ---- K1: a_dst[8192][192] (fp16) = embed(dst) @ w1bc + bias_c ----
__global__ __launch_bounds__(256) void k1_dst(const int* __restrict__ dst_idx,
    const float* __restrict__ feat, const float* __restrict__ pos,
    const _Float16* __restrict__ w1bc, const float* __restrict__ bias_c,
    _Float16* __restrict__ a_dst){
  __shared__ _Float16 sA[64][SAW];
  __shared__ float sPos[64][3];
  __shared__ float sOmg[32];
  int blk = blockIdx.x, t = threadIdx.x;
  if (t < 32) sOmg[t] = EXP2F((float)t * NEG_L2_10K_O32) * INV_2PI;
  if (t < 64){
    int node = dst_idx[(blk*64 + t) * DEG];
    sPos[t][0] = pos[3*node]; sPos[t][1] = pos[3*node+1]; sPos[t][2] = pos[3*node+2];
  }
  if (t >= 192){
    int e = t - 192;
    int node = dst_idx[(blk*64 + e) * DEG];
    float f0 = feat[3*node], f1 = feat[3*node+1], f2 = feat[3*node+2];
    int4v v0; v0[0] = pkh(f0, f1); v0[1] = pkh(f2, 0.f); v0[2] = 0; v0[3] = 0;
    int4v z; z[0] = 0; z[1] = 0; z[2] = 0; z[3] = 0;
    *reinterpret_cast<int4v*>(&sA[e][192]) = v0;
    *reinterpret_cast<int4v*>(&sA[e][200]) = z;
    *reinterpret_cast<int4v*>(&sA[e][208]) = z;
    *reinterpret_cast<int4v*>(&sA[e][216]) = z;
  }
  __syncthreads();
  tile_trig(sA, sPos, sOmg, t);
  __syncthreads();
  int wave = t >> 6, lane = t & 63, ln15 = lane & 15, grp = lane >> 4;
  f32x4 acc[4][3];
  #pragma unroll
  for (int m = 0; m < 4; m++)
    #pragma unroll
    for (int n = 0; n < 3; n++) acc[m][n] = (f32x4){0.f, 0.f, 0.f, 0.f};
  gemm_tile(acc, sA, w1bc, ln15, grp, wave);
  #pragma unroll
  for (int n = 0; n < 3; n++){
    int col = wave*48 + n*16 + ln15;
    float bias = bias_c[col];
    #pragma unroll
    for (int m = 0; m < 4; m++)
      #pragma unroll
      for (int r = 0; r < 4; r++)
        a_dst[(blk*64 + m*16 + grp*4 + r)*192 + col] = (_Float16)(acc[m][n][r] + bias);
  }
}

// ---- K2: pipelined 8-tile edge kernel ----
__global__ __launch_bounds__(256) void k2_edge(const int* __restrict__ src_idx,
    const float* __restrict__ feat, const float* __restrict__ pos,
    const _Float16* __restrict__ w1tc, const _Float16* __restrict__ a_dst,
    _Float16* __restrict__ S1){
  __shared__ _Float16 sA[2][64][SAW];
  __shared__ float sPos[2][64][3];
  __shared__ float sOmg[32];
  int blk = blockIdx.x, t = threadIdx.x;
  int wave = t >> 6, lane = t & 63, ln15 = lane & 15, grp = lane >> 4;
  int e0 = blk * (TILES*64);

  if (t < 32) sOmg[t] = EXP2F((float)t * NEG_L2_10K_O32) * INV_2PI;

  // B preload: 21 half8, amortized over 8 tiles
  half8 Breg[21];
  {
    const _Float16* bp = w1tc + (wave*48 + ln15)*224 + grp*8;
    #pragma unroll
    for (int n = 0; n < 3; n++)
      #pragma unroll
      for (int k6 = 0; k6 < 7; k6++)
        Breg[n*7 + k6] = *reinterpret_cast<const half8*>(bp + n*16*224 + k6*32);
  }

  float g0 = 0.f, g1 = 0.f, g2 = 0.f;
  // prologue: gather tile 0 and write into buffer 0
  if (t < 64){
    int node = src_idx[e0 + t];
    g0 = pos[3*node]; g1 = pos[3*node+1]; g2 = pos[3*node+2];
    sPos[0][t][0] = g0; sPos[0][t][1] = g1; sPos[0][t][2] = g2;
  } else if (t >= 192){
    int e = t - 192;
    int node = src_idx[e0 + e];
    g0 = feat[3*node]; g1 = feat[3*node+1]; g2 = feat[3*node+2];
    int4v v0; v0[0] = pkh(g0, g1); v0[1] = pkh(g2, 0.f); v0[2] = 0; v0[3] = 0;
    int4v z; z[0] = 0; z[1] = 0; z[2] = 0; z[3] = 0;
    *reinterpret_cast<int4v*>(&sA[0][e][192]) = v0;
    *reinterpret_cast<int4v*>(&sA[0][e][200]) = z;
    *reinterpret_cast<int4v*>(&sA[0][e][208]) = z;
    *reinterpret_cast<int4v*>(&sA[0][e][216]) = z;
  }
  __syncthreads();

  for (int tl = 0; tl < TILES; ++tl){
    int cur = tl & 1;
    // 1) issue gather for tile tl+1 (regs only; consumed at step 6)
    if (tl + 1 < TILES){
      if (t < 64){
        int node = src_idx[e0 + (tl+1)*64 + t];
        g0 = pos[3*node]; g1 = pos[3*node+1]; g2 = pos[3*node+2];
      } else if (t >= 192){
        int node = src_idx[e0 + (tl+1)*64 + (t-192)];
        g0 = feat[3*node]; g1 = feat[3*node+1]; g2 = feat[3*node+2];
      }
    }
    // 2) a_dst prefetch for this tile (consumed in epilogue)
    float ad[2][3];
    {
      const _Float16* adp = a_dst + (blk*TILES + tl)*2*192 + wave*48 + ln15;
      #pragma unroll
      for (int h = 0; h < 2; h++)
        #pragma unroll
        for (int n = 0; n < 3; n++)
          ad[h][n] = (float)adp[h*192 + n*16];
    }
    // 3) trig fill current tile
    tile_trig(sA[cur], sPos[cur], sOmg, t);
    __syncthreads();
    // 4) MFMA on sA[cur]
    f32x4 acc[4][3];
    #pragma unroll
    for (int m = 0; m < 4; m++)
      #pragma unroll
      for (int n = 0; n < 3; n++) acc[m][n] = (f32x4){0.f, 0.f, 0.f, 0.f};
    #pragma unroll
    for (int k6 = 0; k6 < 7; k6++){
      half8 Af[4];
      #pragma unroll
      for (int m = 0; m < 4; m++)
        Af[m] = *reinterpret_cast<const half8*>(&sA[cur][m*16 + ln15][k6*32 + grp*8]);
      #pragma unroll
      for (int n = 0; n < 3; n++)
        #pragma unroll
        for (int m = 0; m < 4; m++)
          acc[m][n] = __builtin_amdgcn_mfma_f32_16x16x32_f16(Af[m], Breg[n*7 + k6], acc[m][n], 0, 0, 0);
    }
    // 5) epilogue: gelu + row-sum per supernode half
    #pragma unroll
    for (int h = 0; h < 2; h++){
      #pragma unroll
      for (int n = 0; n < 3; n++){
        float cs = 0.f;
        #pragma unroll
        for (int mm = 0; mm < 2; mm++){
          f32x4 a = acc[h*2 + mm][n];
          #pragma unroll
          for (int r = 0; r < 4; r++) cs += gelu_f(a[r] + ad[h][n]);
        }
        cs += __shfl_xor(cs, 16, 64);
        cs += __shfl_xor(cs, 32, 64);
        if (grp == 0)
          S1[((blk*TILES + tl)*2 + h)*192 + wave*48 + n*16 + ln15] = (_Float16)cs;
      }
    }
    // 6) write gathered tile tl+1 into the other buffer (vmcnt covered by 3-5)
    if (tl + 1 < TILES){
      int nxt = cur ^ 1;
      if (t < 64){
        sPos[nxt][t][0] = g0; sPos[nxt][t][1] = g1; sPos[nxt][t][2] = g2;
      } else if (t >= 192){
        int e = t - 192;
        int4v v0; v0[0] = pkh(g0, g1); v0[1] = pkh(g2, 0.f); v0[2] = 0; v0[3] = 0;
        int4v z; z[0] = 0; z[1] = 0; z[2] = 0; z[3] = 0;
        *reinterpret_cast<int4v*>(&sA[nxt][e][192]) = v0;
        *reinterpret_cast<int4v*>(&sA[nxt][e][200]) = z;
        *reinterpret_cast<int4v*>(&sA[nxt][e][208]) = z;
        *reinterpret_cast<int4v*>(&sA[nxt][e][216]) = z;
      }
    }
    __syncthreads();
  }
}

// ---- K3: out[8192][192] = S1 @ (W2/32) + b2 ----
__global__ __launch_bounds__(256) void k3_out(const _Float16* __restrict__ S1,
    const _Float16* __restrict__ w2t, const float* __restrict__ b2,
    float* __restrict__ out){
  int blk = blockIdx.x, t = threadIdx.x;
  int wave = t >> 6, lane = t & 63, ln15 = lane & 15, grp = lane >> 4;
  f32x4 acc[4][3];
  #pragma unroll
  for (int m = 0; m < 4; m++)
    #pragma unroll
    for (int n = 0; n < 3; n++) acc[m][n] = (f32x4){0.f, 0.f, 0.f, 0.f};
  #pragma unroll
  for (int k6 = 0; k6 < 6; k6++){
    half8 Af[4];
    #pragma unroll
    for (int m = 0; m < 4; m++)
      Af[m] = *reinterpret_cast<const half8*>(S1 + (blk*64 + m*16 + ln15)*192 + k6*32 + grp*8);
    #pragma unroll
    for (int n = 0; n < 3; n++){
      half8 Bf = *reinterpret_cast<const half8*>(w2t + (wave*48 + n*16 + ln15)*192 + k6*32 + grp*8);
      #pragma unroll
      for (int m = 0; m < 4; m++)
        acc[m][n] = __builtin_amdgcn_mfma_f32_16x16x32_f16(Af[m], Bf, acc[m][n], 0, 0, 0);
    }
  }
  #pragma unroll
  for (int n = 0; n < 3; n++){
    int col = wave*48 + n*16 + ln15;
    float bias = b2[col];
    #pragma unroll
    for (int m = 0; m < 4; m++)
      #pragma unroll
      for (int r = 0; r < 4; r++)
        out[(blk*64 + m*16 + grp*4 + r)*192 + col] = acc[m][n][r] + bias;
  }
}

extern "C" void kernel_launch(void* const* d_in, const int* in_sizes, int n_in,
                              void* d_out, int out_size, void* d_ws, size_t ws_size,
                              hipStream_t stream) {
  const float* feat   = (const float*)d_in[0];
  const float* pos    = (const float*)d_in[1];
  const int*   src_i  = (const int*)  d_in[2];
  const int*   dst_i  = (const int*)  d_in[3];
  const float* W_in   = (const float*)d_in[4];
  const float* b_in   = (const float*)d_in[5];
  const float* W1     = (const float*)d_in[6];
  const float* b1     = (const float*)d_in[7];
  const float* W2     = (const float*)d_in[8];
  const float* b2     = (const float*)d_in[9];
  float* out = (float*)d_out;

  char* ws = (char*)d_ws;
  _Float16* w1tc   = (_Float16*)(ws);                 // 192*224*2 =  86016 B
  _Float16* w1bc   = (_Float16*)(ws + 86016);         //              86016 B
  _Float16* w2t    = (_Float16*)(ws + 172032);        // 192*192*2 =  73728 B
  float*    bias_c = (float*)   (ws + 245760);        //                768 B
  _Float16* a_dst  = (_Float16*)(ws + 246528);        // 8192*192*2 = 3145728 B
  _Float16* S1     = (_Float16*)(ws + 3392256);       // 8192*192*2 = 3145728 B
  // total ws use: 6537984 B

  k0_prep<<<816, 256, 0, stream>>>(W_in, b_in, W1, b1, W2, w1tc, w1bc, w2t, bias_c);
  k1_dst <<<128, 256, 0, stream>>>(dst_i, feat, pos, w1bc, bias_c, a_dst);
  k2_edge<<<512, 256, 0, stream>>>(src_i, feat, pos, w1tc, a_dst, S1);
  k3_out <<<128, 256, 0, stream>>>(S1, w2t, b2, out);
}